// Round 5
// baseline (831.357 us; speedup 1.0000x reference)
//
#include <hip/hip_runtime.h>
#include <cstdint>
#include <cstddef>

#define NNODES 100000
#define NEDGES 1600000
// D = 128, C = 128 (hard-coded below)

typedef float f32x4 __attribute__((ext_vector_type(4)));
// native fp16 (no hip_fp16.h dependency — clang _Float16)
typedef _Float16 f16x2 __attribute__((ext_vector_type(2)));
typedef _Float16 f16x4 __attribute__((ext_vector_type(4)));
typedef _Float16 f16x8 __attribute__((ext_vector_type(8)));

// ---------------------------------------------------------------- utilities

__global__ void zero_int_kernel(int* __restrict__ p, int n) {
  int i = blockIdx.x * blockDim.x + threadIdx.x;
  if (i < n) p[i] = 0;
}

// int64 vs int32 edge_index detection (high words all zero => int64)
__global__ void detect_kernel(const unsigned int* __restrict__ ei, int* __restrict__ flag) {
  unsigned int v = ei[2 * threadIdx.x + 1];
  unsigned long long b = __ballot(v != 0u);
  if (threadIdx.x == 0) *flag = (b == 0ull) ? 1 : 0;
}

__device__ __forceinline__ int edge_val(const void* ei, int is64, long long idx) {
  if (is64) return (int)((const long long*)ei)[idx];
  return ((const int*)ei)[idx];
}

// ---------------------------------------------------------------- edge compaction
// edge_index (int64 or int32) -> src32/dst32 int32 arrays (12.8 MB total, L3-resident).

__global__ void compact_kernel(const void* __restrict__ ei, const int* __restrict__ flag,
                               int* __restrict__ src32, int* __restrict__ dst32) {
  const int is64 = *flag;
  for (int e = blockIdx.x * blockDim.x + threadIdx.x; e < NEDGES;
       e += gridDim.x * blockDim.x) {
    src32[e] = edge_val(ei, is64, e);
    dst32[e] = edge_val(ei, is64, (long long)NEDGES + e);
  }
}

// ---------------------------------------------------------------- degree / CSR

__global__ void hist32_kernel(const int* __restrict__ dst32, int* __restrict__ counts) {
  for (int e = blockIdx.x * blockDim.x + threadIdx.x; e < NEDGES;
       e += gridDim.x * blockDim.x) {
    int d = __builtin_nontemporal_load(&dst32[e]);
    atomicAdd(&counts[d], 1);
  }
}

__global__ void dinv_kernel(const int* __restrict__ counts, float* __restrict__ dinv) {
  int i = blockIdx.x * blockDim.x + threadIdx.x;
  if (i < NNODES) dinv[i] = rsqrtf((float)(counts[i] + 1));  // +1 self loop
}

#define SCAN_B 256
#define SCAN_TILE 1024

__global__ void scan_reduce_kernel(const int* __restrict__ counts, int* __restrict__ bsums) {
  __shared__ int sd[SCAN_B];
  int t = threadIdx.x;
  int base = blockIdx.x * SCAN_TILE + t * 4;
  int s = 0;
#pragma unroll
  for (int i = 0; i < 4; i++) {
    int idx = base + i;
    if (idx < NNODES) s += counts[idx];
  }
  sd[t] = s;
  __syncthreads();
  for (int o = SCAN_B / 2; o > 0; o >>= 1) {
    if (t < o) sd[t] += sd[t + o];
    __syncthreads();
  }
  if (t == 0) bsums[blockIdx.x] = sd[0];
}

__global__ void scan_bsums_kernel(int* __restrict__ bsums, int* __restrict__ offs, int nb) {
  if (threadIdx.x == 0 && blockIdx.x == 0) {
    int run = 0;
    for (int b = 0; b < nb; b++) {
      int v = bsums[b];
      bsums[b] = run;
      run += v;
    }
    offs[NNODES] = run;
  }
}

__global__ void scan_write_kernel(const int* __restrict__ counts, const int* __restrict__ bsums,
                                  int* __restrict__ offs) {
  __shared__ int sd[SCAN_B];
  int t = threadIdx.x;
  int base = blockIdx.x * SCAN_TILE + t * 4;
  int v[4];
  int s = 0;
#pragma unroll
  for (int i = 0; i < 4; i++) {
    int idx = base + i;
    v[i] = (idx < NNODES) ? counts[idx] : 0;
    s += v[i];
  }
  sd[t] = s;
  __syncthreads();
  for (int o = 1; o < SCAN_B; o <<= 1) {
    int x = (t >= o) ? sd[t - o] : 0;
    __syncthreads();
    sd[t] += x;
    __syncthreads();
  }
  int run = sd[t] - s + bsums[blockIdx.x];
#pragma unroll
  for (int i = 0; i < 4; i++) {
    int idx = base + i;
    if (idx < NNODES) {
      offs[idx] = run;
      run += v[i];
    }
  }
}

// Destination-partitioned CSR fill.
// Group g = blockIdx%8 (lands on XCD g under round-robin dispatch — perf heuristic only)
// handles only dst in [g*12500, (g+1)*12500). All writes to a given csr cache line then
// flow through ONE XCD's L2 -> lines fill completely, evict once: HBM write ~6.4 MB
// instead of 107 MB (sector-amplified random scatter). Each group scans the full
// (compacted, L3-resident) edge list with nontemporal reads so the stream doesn't
// evict the csr write window.

__global__ __launch_bounds__(256) void fill_part_kernel(const int* __restrict__ src32,
                                                        const int* __restrict__ dst32,
                                                        const int* __restrict__ offs,
                                                        int* __restrict__ fillc,
                                                        int* __restrict__ csr) {
  const int g = blockIdx.x & 7;      // XCD id under round-robin dispatch
  const int inb = blockIdx.x >> 3;   // 0..127 within group
  const int gs = NNODES / 8;         // 12500 nodes per group
  const int lo = g * gs;
  const int hi = lo + gs;
  const int per = NEDGES / 128;      // 12500 edges per in-group block
  const int e0 = inb * per;
  const int e1 = e0 + per;
  for (int e = e0 + (int)threadIdx.x; e < e1; e += 256) {
    int d = __builtin_nontemporal_load(&dst32[e]);
    if (d >= lo && d < hi) {
      int s = __builtin_nontemporal_load(&src32[e]);
      int pos = offs[d] + atomicAdd(&fillc[d], 1);
      csr[pos] = s;
    }
  }
}

// ---------------------------------------------------------------- prescale (fp16 out)
// y[i,:] = (fp16) dinv[i] * x[i,:]

__global__ void prescale_half_kernel(const float* __restrict__ x, const float* __restrict__ dinv,
                                     f16x4* __restrict__ y) {
  int i = blockIdx.x * blockDim.x + threadIdx.x;  // over NNODES*32 float4
  if (i >= NNODES * 32) return;
  int row = i >> 5;
  float s = dinv[row];
  float4 v = ((const float4*)x)[i];
  f16x4 h;
  h[0] = (_Float16)(v.x * s);
  h[1] = (_Float16)(v.y * s);
  h[2] = (_Float16)(v.z * s);
  h[3] = (_Float16)(v.w * s);
  y[i] = h;
}

// ---------------------------------------------------------------- aggregation (gather, fp16 in)
// Input rows are PRE-SCALED fp16: y_j = (fp16)(dinv[j]*x_j).   256 B/row.
// out[i,:] = dinv[i] * (y_i + sum_{j in nbr(i)} y_j) + bias   (fp32 accumulate)
// out_half: write fp16 (feeds the next GEMM's fp16 A path), else fp32.
// One wave per node, f16x2 per lane, 8-way unrolled gathers (4 fp32 accumulators).

__device__ __forceinline__ float2 f16x2_to_f32(f16x2 h) {
  return make_float2((float)h[0], (float)h[1]);
}

__global__ __launch_bounds__(256) void aggregate_half_kernel(
    const f16x2* __restrict__ in, void* __restrict__ out, int out_half,
    const int* __restrict__ offs, const int* __restrict__ csr, const float* __restrict__ dinv,
    const float* __restrict__ bias) {
  int node = blockIdx.x * 4 + (threadIdx.x >> 6);
  if (node >= NNODES) return;
  int ch = threadIdx.x & 63;  // f16x2 index within row (64 x f16x2 = 128 cols)
  int beg = offs[node], end = offs[node + 1];

  // self term (pre-scaled row)
  float2 a0 = f16x2_to_f32(in[(size_t)node * 64 + ch]);
  float2 a1 = make_float2(0.f, 0.f);
  float2 a2 = make_float2(0.f, 0.f);
  float2 a3 = make_float2(0.f, 0.f);

  int p = beg;
  for (; p + 8 <= end; p += 8) {
    int j0 = csr[p + 0], j1 = csr[p + 1], j2 = csr[p + 2], j3 = csr[p + 3];
    int j4 = csr[p + 4], j5 = csr[p + 5], j6 = csr[p + 6], j7 = csr[p + 7];
    f16x2 h0 = in[(size_t)j0 * 64 + ch];
    f16x2 h1 = in[(size_t)j1 * 64 + ch];
    f16x2 h2 = in[(size_t)j2 * 64 + ch];
    f16x2 h3 = in[(size_t)j3 * 64 + ch];
    f16x2 h4 = in[(size_t)j4 * 64 + ch];
    f16x2 h5 = in[(size_t)j5 * 64 + ch];
    f16x2 h6 = in[(size_t)j6 * 64 + ch];
    f16x2 h7 = in[(size_t)j7 * 64 + ch];
    float2 v0 = f16x2_to_f32(h0);
    float2 v1 = f16x2_to_f32(h1);
    float2 v2 = f16x2_to_f32(h2);
    float2 v3 = f16x2_to_f32(h3);
    float2 v4 = f16x2_to_f32(h4);
    float2 v5 = f16x2_to_f32(h5);
    float2 v6 = f16x2_to_f32(h6);
    float2 v7 = f16x2_to_f32(h7);
    a0.x += v0.x; a0.y += v0.y;
    a1.x += v1.x; a1.y += v1.y;
    a2.x += v2.x; a2.y += v2.y;
    a3.x += v3.x; a3.y += v3.y;
    a0.x += v4.x; a0.y += v4.y;
    a1.x += v5.x; a1.y += v5.y;
    a2.x += v6.x; a2.y += v6.y;
    a3.x += v7.x; a3.y += v7.y;
  }
  for (; p + 2 <= end; p += 2) {
    int j0 = csr[p], j1 = csr[p + 1];
    float2 v0 = f16x2_to_f32(in[(size_t)j0 * 64 + ch]);
    float2 v1 = f16x2_to_f32(in[(size_t)j1 * 64 + ch]);
    a0.x += v0.x; a0.y += v0.y;
    a1.x += v1.x; a1.y += v1.y;
  }
  if (p < end) {
    float2 v0 = f16x2_to_f32(in[(size_t)csr[p] * 64 + ch]);
    a0.x += v0.x; a0.y += v0.y;
  }

  float di = dinv[node];
  int c = ch * 2;
  float2 r;
  r.x = di * (a0.x + a1.x + a2.x + a3.x);
  r.y = di * (a0.y + a1.y + a2.y + a3.y);
  if (bias) {
    r.x += bias[c];
    r.y += bias[c + 1];
  }
  if (out_half) {
    f16x2 h;
    h[0] = (_Float16)r.x;
    h[1] = (_Float16)r.y;
    ((f16x2*)out)[(size_t)node * 64 + ch] = h;
  } else {
    *(float2*)((float*)out + (size_t)node * 128 + c) = r;
  }
}

// ---------------------------------------------------------------- weight prep
// W [K][M] fp32  ->  Wt_h/Wt_l [M][K] fp16 (transposed, split: w = wh + wl, wl ~ 2^-11 w)

__global__ void wprep_f16_kernel(const float* __restrict__ W, int K, int M,
                                 _Float16* __restrict__ th, _Float16* __restrict__ tl) {
  int i = blockIdx.x * blockDim.x + threadIdx.x;
  if (i >= K * M) return;
  int k = i / M, m = i - k * M;
  float x = W[i];
  _Float16 h = (_Float16)x;
  th[(size_t)m * K + k] = h;
  tl[(size_t)m * K + k] = (_Float16)(x - (float)h);
}

// ---------------------------------------------------------------- fp16x2 split MFMA GEMM
// C[n,M] = concat(A0,A1,A2) @ W (+row_scale)(+bias)(+relu).
// A chunks may be fp32 (t=0, converted to fp16 at staging) or fp16 (t=1, pure copy).
// W split into fp16 hi/lo: a*w ~= a*wh + a*wl (2 MFMAs, fp32 accumulate).
// Block 128x128, BK=32, 4 waves each 64x64 (4x4 tiles of 16x16x32 f16 MFMA).
// row_scale: C[r,:] *= row_scale[r] before bias (folds dinv pre-scale of next agg).
// out_half: write fp16 (feeds fp16 A path / aggregation), else fp32.

#define BM 128
#define BN 128
#define BK 32
#define LDT 40

__global__ __launch_bounds__(256) void gemm_f16_kernel(
    const void* __restrict__ A0, int K0, int t0, const void* __restrict__ A1, int K1, int t1,
    const void* __restrict__ A2, int K2, int t2, const _Float16* __restrict__ Bth,
    const _Float16* __restrict__ Btl, int Ktot, int M, const float* __restrict__ bias,
    const float* __restrict__ row_scale, void* __restrict__ Cmat, int relu, int out_half,
    int nrows) {
  __shared__ unsigned short As[BM * LDT];
  __shared__ unsigned short Bs_h[BN * LDT];
  __shared__ unsigned short Bs_l[BN * LDT];

  const int tid = threadIdx.x;
  const int lane = tid & 63;
  const int wv = tid >> 6;
  const int mBase = (wv >> 1) * 64;
  const int nBase = (wv & 1) * 64;
  const int ml = lane & 15;
  const int quad = lane >> 4;
  const int rowBase = blockIdx.x * BM;
  const int colBase = blockIdx.y * BN;

  const int sr = tid >> 1;         // 0..127
  const int skc = (tid & 1) * 16;  // 0 or 16 (halfs)

  f32x4 acc[4][4];
  const f32x4 zero = {0.f, 0.f, 0.f, 0.f};
#pragma unroll
  for (int i = 0; i < 4; i++)
#pragma unroll
    for (int j = 0; j < 4; j++) acc[i][j] = zero;

  for (int k0 = 0; k0 < Ktot; k0 += BK) {
    const void* Ap;
    int kl, Kp, tp;
    if (k0 < K0) {
      Ap = A0; kl = k0; Kp = K0; tp = t0;
    } else if (k0 < K0 + K1) {
      Ap = A1; kl = k0 - K0; Kp = K1; tp = t1;
    } else {
      Ap = A2; kl = k0 - K0 - K1; Kp = K2; tp = t2;
    }
    {
      int gr = rowBase + sr;
      if (gr < nrows) {
        if (tp == 0) {
          // fp32 source: load 16 floats, convert to fp16
          const float* src = (const float*)Ap + (size_t)gr * Kp + kl + skc;
          float4 v0 = ((const float4*)src)[0];
          float4 v1 = ((const float4*)src)[1];
          float4 v2 = ((const float4*)src)[2];
          float4 v3 = ((const float4*)src)[3];
          f16x8 h0, h1;
          h0[0] = (_Float16)v0.x; h0[1] = (_Float16)v0.y;
          h0[2] = (_Float16)v0.z; h0[3] = (_Float16)v0.w;
          h0[4] = (_Float16)v1.x; h0[5] = (_Float16)v1.y;
          h0[6] = (_Float16)v1.z; h0[7] = (_Float16)v1.w;
          h1[0] = (_Float16)v2.x; h1[1] = (_Float16)v2.y;
          h1[2] = (_Float16)v2.z; h1[3] = (_Float16)v2.w;
          h1[4] = (_Float16)v3.x; h1[5] = (_Float16)v3.y;
          h1[6] = (_Float16)v3.z; h1[7] = (_Float16)v3.w;
          *(f16x8*)&As[sr * LDT + skc] = h0;
          *(f16x8*)&As[sr * LDT + skc + 8] = h1;
        } else {
          // fp16 source: pure 32B copy
          const uint4* src = (const uint4*)((const _Float16*)Ap + (size_t)gr * Kp + kl + skc);
          *(uint4*)&As[sr * LDT + skc] = src[0];
          *(uint4*)&As[sr * LDT + skc + 8] = src[1];
        }
      } else {
        uint4 z = make_uint4(0u, 0u, 0u, 0u);
        *(uint4*)&As[sr * LDT + skc] = z;
        *(uint4*)&As[sr * LDT + skc + 8] = z;
      }

      const _Float16* bh = Bth + (size_t)(colBase + sr) * Ktot + k0 + skc;
      const _Float16* bl = Btl + (size_t)(colBase + sr) * Ktot + k0 + skc;
      uint4 u0 = ((const uint4*)bh)[0];
      uint4 u1 = ((const uint4*)bh)[1];
      uint4 w0 = ((const uint4*)bl)[0];
      uint4 w1 = ((const uint4*)bl)[1];
      *(uint4*)&Bs_h[sr * LDT + skc] = u0;
      *(uint4*)&Bs_h[sr * LDT + skc + 8] = u1;
      *(uint4*)&Bs_l[sr * LDT + skc] = w0;
      *(uint4*)&Bs_l[sr * LDT + skc + 8] = w1;
    }
    __syncthreads();

    f16x8 av[4], bh[4], bl[4];
#pragma unroll
    for (int nt = 0; nt < 4; nt++) {
      int nrow = nBase + nt * 16 + ml;
      bh[nt] = *(const f16x8*)&Bs_h[nrow * LDT + quad * 8];
      bl[nt] = *(const f16x8*)&Bs_l[nrow * LDT + quad * 8];
    }
#pragma unroll
    for (int mt = 0; mt < 4; mt++) {
      int mrow = mBase + mt * 16 + ml;
      av[mt] = *(const f16x8*)&As[mrow * LDT + quad * 8];
    }
#pragma unroll
    for (int mt = 0; mt < 4; mt++)
#pragma unroll
      for (int nt = 0; nt < 4; nt++) {
        acc[mt][nt] = __builtin_amdgcn_mfma_f32_16x16x32_f16(av[mt], bh[nt], acc[mt][nt], 0, 0, 0);
        acc[mt][nt] = __builtin_amdgcn_mfma_f32_16x16x32_f16(av[mt], bl[nt], acc[mt][nt], 0, 0, 0);
      }
    __syncthreads();
  }

  // epilogue: C/D layout col=lane&15, row=quad*4+reg
#pragma unroll
  for (int nt = 0; nt < 4; nt++) {
    int col = colBase + nBase + nt * 16 + ml;
    float bv = bias ? bias[col] : 0.f;
#pragma unroll
    for (int mt = 0; mt < 4; mt++) {
      int row0 = rowBase + mBase + mt * 16 + quad * 4;
#pragma unroll
      for (int r = 0; r < 4; r++) {
        int grow = row0 + r;
        if (grow >= nrows) continue;
        float v = acc[mt][nt][r];
        if (row_scale) v *= row_scale[grow];
        v += bv;
        if (relu) v = fmaxf(v, 0.f);
        if (out_half) {
          ((_Float16*)Cmat)[(size_t)grow * M + col] = (_Float16)v;
        } else {
          ((float*)Cmat)[(size_t)grow * M + col] = v;
        }
      }
    }
  }
}

// ---------------------------------------------------------------- launch

extern "C" void kernel_launch(void* const* d_in, const int* in_sizes, int n_in, void* d_out,
                              int out_size, void* d_ws, size_t ws_size, hipStream_t stream) {
  const float* x_self     = (const float*)d_in[0];
  const float* x_neighbor = (const float*)d_in[1];
  const void*  edge_index = d_in[2];
  const float* W_in_self  = (const float*)d_in[3];
  const float* b_in_self  = (const float*)d_in[4];
  const float* W_out_self = (const float*)d_in[5];
  const float* b_out_self = (const float*)d_in[6];
  const float* Wg1        = (const float*)d_in[7];
  const float* bg1        = (const float*)d_in[8];
  const float* Wg2        = (const float*)d_in[9];
  const float* bg2        = (const float*)d_in[10];
  const float* W_out      = (const float*)d_in[11];
  const float* b_out      = (const float*)d_in[12];
  float* out = (float*)d_out;

  char* ws = (char*)d_ws;
  size_t off = 0;
  auto alloc = [&](size_t bytes) -> void* {
    void* p = ws + off;
    off = (off + bytes + 255) & ~(size_t)255;
    return p;
  };
  int* counts = (int*)alloc((size_t)2 * NNODES * 4);  // counts + fillc contiguous
  int* fillc  = counts + NNODES;
  int*   offs   = (int*)alloc((size_t)(NNODES + 1) * 4);
  int*   csr    = (int*)alloc((size_t)NEDGES * 4);
  int*   src32  = (int*)alloc((size_t)NEDGES * 4);
  int*   dst32  = (int*)alloc((size_t)NEDGES * 4);
  int*   bsums  = (int*)alloc(4096);
  int*   flag   = (int*)alloc(256);
  float* dinv   = (float*)alloc((size_t)NNODES * 4);
  _Float16* wt1h = (_Float16*)alloc(32768 * 2);  // W_in_self  K=128 M=256
  _Float16* wt1l = (_Float16*)alloc(32768 * 2);
  _Float16* wt2h = (_Float16*)alloc(49152 * 2);  // W_out_self K=384 M=128
  _Float16* wt2l = (_Float16*)alloc(49152 * 2);
  _Float16* wt3h = (_Float16*)alloc(32768 * 2);  // Wg1        K=128 M=256
  _Float16* wt3l = (_Float16*)alloc(32768 * 2);
  _Float16* wt4h = (_Float16*)alloc(32768 * 2);  // Wg2        K=256 M=128
  _Float16* wt4l = (_Float16*)alloc(32768 * 2);
  _Float16* wt5h = (_Float16*)alloc(65536 * 2);  // W_out      K=512 M=128
  _Float16* wt5l = (_Float16*)alloc(65536 * 2);
  float* bufA = (float*)alloc((size_t)NNODES * 256 * 4);
  float* bufB = (float*)alloc((size_t)NNODES * 256 * 4);
  (void)ws_size;

  const int nb = (NNODES + SCAN_TILE - 1) / SCAN_TILE;  // 98
  const int gridRows = (NNODES + BM - 1) / BM;          // 782

  detect_kernel<<<1, 64, 0, stream>>>((const unsigned int*)edge_index, flag);
  compact_kernel<<<1024, 256, 0, stream>>>(edge_index, flag, src32, dst32);
  zero_int_kernel<<<(2 * NNODES + 255) / 256, 256, 0, stream>>>(counts, 2 * NNODES);
  hist32_kernel<<<1024, 256, 0, stream>>>(dst32, counts);
  dinv_kernel<<<(NNODES + 255) / 256, 256, 0, stream>>>(counts, dinv);
  scan_reduce_kernel<<<nb, SCAN_B, 0, stream>>>(counts, bsums);
  scan_bsums_kernel<<<1, 64, 0, stream>>>(bsums, offs, nb);
  scan_write_kernel<<<nb, SCAN_B, 0, stream>>>(counts, bsums, offs);
  fill_part_kernel<<<1024, 256, 0, stream>>>(src32, dst32, offs, fillc, csr);

  wprep_f16_kernel<<<(32768 + 255) / 256, 256, 0, stream>>>(W_in_self, 128, 256, wt1h, wt1l);
  wprep_f16_kernel<<<(49152 + 255) / 256, 256, 0, stream>>>(W_out_self, 384, 128, wt2h, wt2l);
  wprep_f16_kernel<<<(32768 + 255) / 256, 256, 0, stream>>>(Wg1, 128, 256, wt3h, wt3l);
  wprep_f16_kernel<<<(32768 + 255) / 256, 256, 0, stream>>>(Wg2, 256, 128, wt4h, wt4l);
  wprep_f16_kernel<<<(65536 + 255) / 256, 256, 0, stream>>>(W_out, 512, 128, wt5h, wt5l);

  // ---- dense self branch ----
  // l1 = relu(x_self @ W1 + b1) stored fp16 [N,256] in bufA
  _Float16* l1 = (_Float16*)bufA;
  gemm_f16_kernel<<<dim3(gridRows, 2), 256, 0, stream>>>(
      x_self, 128, 0, nullptr, 0, 0, nullptr, 0, 0, wt1h, wt1l, 128, 256, b_in_self, nullptr,
      l1, 1, 1, NNODES);
  gemm_f16_kernel<<<dim3(gridRows, 1), 256, 0, stream>>>(
      x_self, 128, 0, l1, 256, 1, nullptr, 0, 0, wt2h, wt2l, 384, 128, b_out_self, nullptr,
      out, 0, 0, NNODES);

  // ---- GCN branch (A_norm @ (X W) == (A_norm @ X) W), all intermediates fp16 ----
  // Buffer timeline:
  //   ybuf = bufB [N,128] f16 (dead after agg1)
  //   aggx = bufA [N,128] f16 (bufA free after GEMM-2; dead after GEMM-3)
  //   g1   = bufB [N,256] f16 (overwrites ybuf; live through GEMM-5)
  //   xw2  = bufA [N,128] f16 (dead after agg2)
  //   g2   = bufA + N*128 halfs, [N,128] f16 (no overlap with xw2)
  _Float16* ybuf = (_Float16*)bufB;
  _Float16* aggx = (_Float16*)bufA;
  _Float16* g1   = (_Float16*)bufB;
  _Float16* xw2  = (_Float16*)bufA;
  _Float16* g2   = (_Float16*)bufA + (size_t)NNODES * 128;

  prescale_half_kernel<<<(NNODES * 32 + 255) / 256, 256, 0, stream>>>(x_neighbor, dinv,
                                                                     (f16x4*)ybuf);
  aggregate_half_kernel<<<NNODES / 4, 256, 0, stream>>>((const f16x2*)ybuf, aggx, 1, offs, csr,
                                                        dinv, nullptr);
  gemm_f16_kernel<<<dim3(gridRows, 2), 256, 0, stream>>>(
      aggx, 128, 1, nullptr, 0, 0, nullptr, 0, 0, wt3h, wt3l, 128, 256, bg1, nullptr, g1, 0, 1,
      NNODES);
  // xw2 = (fp16)((g1 @ Wg2) * dinv[row])  (pre-scale for agg2 folded into epilogue)
  gemm_f16_kernel<<<dim3(gridRows, 1), 256, 0, stream>>>(
      g1, 256, 1, nullptr, 0, 0, nullptr, 0, 0, wt4h, wt4l, 256, 128, nullptr, dinv, xw2, 0, 1,
      NNODES);
  aggregate_half_kernel<<<NNODES / 4, 256, 0, stream>>>((const f16x2*)xw2, g2, 1, offs, csr,
                                                        dinv, bg2);
  gemm_f16_kernel<<<dim3(gridRows, 1), 256, 0, stream>>>(
      x_neighbor, 128, 0, g1, 256, 1, g2, 128, 1, wt5h, wt5l, 512, 128, b_out, nullptr,
      out + (size_t)NNODES * 128, 0, 0, NNODES);
}

// Round 6
// 788.833 us; speedup vs baseline: 1.0539x; 1.0539x over previous
//
#include <hip/hip_runtime.h>
#include <cstdint>
#include <cstddef>

#define NNODES 100000
#define NEDGES 1600000
// D = 128, C = 128 (hard-coded below)

typedef float f32x4 __attribute__((ext_vector_type(4)));
typedef unsigned int u32;
// native fp16 (no hip_fp16.h dependency — clang _Float16)
typedef _Float16 f16x2 __attribute__((ext_vector_type(2)));
typedef _Float16 f16x4 __attribute__((ext_vector_type(4)));
typedef _Float16 f16x8 __attribute__((ext_vector_type(8)));

// async global->LDS, 16B per lane: dest = lds_base + lane*16 (linear), src per-lane.
__device__ __forceinline__ void gload_lds16(const void* g, void* l) {
  __builtin_amdgcn_global_load_lds((const __attribute__((address_space(1))) u32*)g,
                                   (__attribute__((address_space(3))) u32*)l, 16, 0, 0);
}

// ---------------------------------------------------------------- utilities

__global__ void zero_int_kernel(int* __restrict__ p, int n) {
  int i = blockIdx.x * blockDim.x + threadIdx.x;
  if (i < n) p[i] = 0;
}

// int64 vs int32 edge_index detection (high words all zero => int64)
__global__ void detect_kernel(const unsigned int* __restrict__ ei, int* __restrict__ flag) {
  unsigned int v = ei[2 * threadIdx.x + 1];
  unsigned long long b = __ballot(v != 0u);
  if (threadIdx.x == 0) *flag = (b == 0ull) ? 1 : 0;
}

__device__ __forceinline__ int edge_val(const void* ei, int is64, long long idx) {
  if (is64) return (int)((const long long*)ei)[idx];
  return ((const int*)ei)[idx];
}

// ---------------------------------------------------------------- degree / CSR

__global__ void hist_kernel(const void* __restrict__ ei, const int* __restrict__ flag,
                            int* __restrict__ counts) {
  const int is64 = *flag;
  for (long long e = (long long)blockIdx.x * blockDim.x + threadIdx.x; e < NEDGES;
       e += (long long)gridDim.x * blockDim.x) {
    int d = edge_val(ei, is64, NEDGES + e);
    atomicAdd(&counts[d], 1);
  }
}

__global__ void dinv_kernel(const int* __restrict__ counts, float* __restrict__ dinv) {
  int i = blockIdx.x * blockDim.x + threadIdx.x;
  if (i < NNODES) dinv[i] = rsqrtf((float)(counts[i] + 1));  // +1 self loop
}

#define SCAN_B 256
#define SCAN_TILE 1024

__global__ void scan_reduce_kernel(const int* __restrict__ counts, int* __restrict__ bsums) {
  __shared__ int sd[SCAN_B];
  int t = threadIdx.x;
  int base = blockIdx.x * SCAN_TILE + t * 4;
  int s = 0;
#pragma unroll
  for (int i = 0; i < 4; i++) {
    int idx = base + i;
    if (idx < NNODES) s += counts[idx];
  }
  sd[t] = s;
  __syncthreads();
  for (int o = SCAN_B / 2; o > 0; o >>= 1) {
    if (t < o) sd[t] += sd[t + o];
    __syncthreads();
  }
  if (t == 0) bsums[blockIdx.x] = sd[0];
}

__global__ void scan_bsums_kernel(int* __restrict__ bsums, int* __restrict__ offs, int nb) {
  if (threadIdx.x == 0 && blockIdx.x == 0) {
    int run = 0;
    for (int b = 0; b < nb; b++) {
      int v = bsums[b];
      bsums[b] = run;
      run += v;
    }
    offs[NNODES] = run;
  }
}

__global__ void scan_write_kernel(const int* __restrict__ counts, const int* __restrict__ bsums,
                                  int* __restrict__ offs) {
  __shared__ int sd[SCAN_B];
  int t = threadIdx.x;
  int base = blockIdx.x * SCAN_TILE + t * 4;
  int v[4];
  int s = 0;
#pragma unroll
  for (int i = 0; i < 4; i++) {
    int idx = base + i;
    v[i] = (idx < NNODES) ? counts[idx] : 0;
    s += v[i];
  }
  sd[t] = s;
  __syncthreads();
  for (int o = 1; o < SCAN_B; o <<= 1) {
    int x = (t >= o) ? sd[t - o] : 0;
    __syncthreads();
    sd[t] += x;
    __syncthreads();
  }
  int run = sd[t] - s + bsums[blockIdx.x];
#pragma unroll
  for (int i = 0; i < 4; i++) {
    int idx = base + i;
    if (idx < NNODES) {
      offs[idx] = run;
      run += v[i];
    }
  }
}

__global__ void fill_kernel(const void* __restrict__ ei, const int* __restrict__ flag,
                            const int* __restrict__ offs, int* __restrict__ fillc,
                            int* __restrict__ csr) {
  const int is64 = *flag;
  for (long long e = (long long)blockIdx.x * blockDim.x + threadIdx.x; e < NEDGES;
       e += (long long)gridDim.x * blockDim.x) {
    int s = edge_val(ei, is64, e);
    int d = edge_val(ei, is64, NEDGES + e);
    int pos = offs[d] + atomicAdd(&fillc[d], 1);
    csr[pos] = s;
  }
}

// ---------------------------------------------------------------- fp32 -> fp16 convert
// y[i] = (fp16) x[i], vectorized float4 -> f16x4

__global__ void xcvt_kernel(const float* __restrict__ x, f16x4* __restrict__ y, int n4) {
  int i = blockIdx.x * blockDim.x + threadIdx.x;
  if (i >= n4) return;
  float4 v = ((const float4*)x)[i];
  f16x4 h;
  h[0] = (_Float16)v.x;
  h[1] = (_Float16)v.y;
  h[2] = (_Float16)v.z;
  h[3] = (_Float16)v.w;
  y[i] = h;
}

// ---------------------------------------------------------------- prescale (fp16 in/out)
// y[i,:] = (fp16) dinv[i] * x16[i,:]

__global__ void prescale16_kernel(const f16x4* __restrict__ x, const float* __restrict__ dinv,
                                  f16x4* __restrict__ y) {
  int i = blockIdx.x * blockDim.x + threadIdx.x;  // over NNODES*32 f16x4
  if (i >= NNODES * 32) return;
  int row = i >> 5;
  float s = dinv[row];
  f16x4 v = x[i];
  f16x4 h;
  h[0] = (_Float16)((float)v[0] * s);
  h[1] = (_Float16)((float)v[1] * s);
  h[2] = (_Float16)((float)v[2] * s);
  h[3] = (_Float16)((float)v[3] * s);
  y[i] = h;
}

// ---------------------------------------------------------------- aggregation (gather, fp16 in)
// Input rows are PRE-SCALED fp16: y_j = (fp16)(dinv[j]*x_j).   256 B/row.
// out[i,:] = dinv[i] * (y_i + sum_{j in nbr(i)} y_j) + bias   (fp32 accumulate)
// out_half: write fp16 (feeds the next GEMM's fp16 A path), else fp32.
// One wave per node, f16x2 per lane, 8-way unrolled gathers (4 fp32 accumulators).

__device__ __forceinline__ float2 f16x2_to_f32(f16x2 h) {
  return make_float2((float)h[0], (float)h[1]);
}

__global__ __launch_bounds__(256) void aggregate_half_kernel(
    const f16x2* __restrict__ in, void* __restrict__ out, int out_half,
    const int* __restrict__ offs, const int* __restrict__ csr, const float* __restrict__ dinv,
    const float* __restrict__ bias) {
  int node = blockIdx.x * 4 + (threadIdx.x >> 6);
  if (node >= NNODES) return;
  int ch = threadIdx.x & 63;  // f16x2 index within row (64 x f16x2 = 128 cols)
  int beg = offs[node], end = offs[node + 1];

  // self term (pre-scaled row)
  float2 a0 = f16x2_to_f32(in[(size_t)node * 64 + ch]);
  float2 a1 = make_float2(0.f, 0.f);
  float2 a2 = make_float2(0.f, 0.f);
  float2 a3 = make_float2(0.f, 0.f);

  int p = beg;
  for (; p + 8 <= end; p += 8) {
    int j0 = csr[p + 0], j1 = csr[p + 1], j2 = csr[p + 2], j3 = csr[p + 3];
    int j4 = csr[p + 4], j5 = csr[p + 5], j6 = csr[p + 6], j7 = csr[p + 7];
    f16x2 h0 = in[(size_t)j0 * 64 + ch];
    f16x2 h1 = in[(size_t)j1 * 64 + ch];
    f16x2 h2 = in[(size_t)j2 * 64 + ch];
    f16x2 h3 = in[(size_t)j3 * 64 + ch];
    f16x2 h4 = in[(size_t)j4 * 64 + ch];
    f16x2 h5 = in[(size_t)j5 * 64 + ch];
    f16x2 h6 = in[(size_t)j6 * 64 + ch];
    f16x2 h7 = in[(size_t)j7 * 64 + ch];
    float2 v0 = f16x2_to_f32(h0);
    float2 v1 = f16x2_to_f32(h1);
    float2 v2 = f16x2_to_f32(h2);
    float2 v3 = f16x2_to_f32(h3);
    float2 v4 = f16x2_to_f32(h4);
    float2 v5 = f16x2_to_f32(h5);
    float2 v6 = f16x2_to_f32(h6);
    float2 v7 = f16x2_to_f32(h7);
    a0.x += v0.x; a0.y += v0.y;
    a1.x += v1.x; a1.y += v1.y;
    a2.x += v2.x; a2.y += v2.y;
    a3.x += v3.x; a3.y += v3.y;
    a0.x += v4.x; a0.y += v4.y;
    a1.x += v5.x; a1.y += v5.y;
    a2.x += v6.x; a2.y += v6.y;
    a3.x += v7.x; a3.y += v7.y;
  }
  for (; p + 2 <= end; p += 2) {
    int j0 = csr[p], j1 = csr[p + 1];
    float2 v0 = f16x2_to_f32(in[(size_t)j0 * 64 + ch]);
    float2 v1 = f16x2_to_f32(in[(size_t)j1 * 64 + ch]);
    a0.x += v0.x; a0.y += v0.y;
    a1.x += v1.x; a1.y += v1.y;
  }
  if (p < end) {
    float2 v0 = f16x2_to_f32(in[(size_t)csr[p] * 64 + ch]);
    a0.x += v0.x; a0.y += v0.y;
  }

  float di = dinv[node];
  int c = ch * 2;
  float2 r;
  r.x = di * (a0.x + a1.x + a2.x + a3.x);
  r.y = di * (a0.y + a1.y + a2.y + a3.y);
  if (bias) {
    r.x += bias[c];
    r.y += bias[c + 1];
  }
  if (out_half) {
    f16x2 h;
    h[0] = (_Float16)r.x;
    h[1] = (_Float16)r.y;
    ((f16x2*)out)[(size_t)node * 64 + ch] = h;
  } else {
    *(float2*)((float*)out + (size_t)node * 128 + c) = r;
  }
}

// ---------------------------------------------------------------- weight prep
// W [K][M] fp32  ->  Wt_h/Wt_l [M][K] fp16 (transposed, split: w = wh + wl, wl ~ 2^-11 w)

__global__ void wprep_f16_kernel(const float* __restrict__ W, int K, int M,
                                 _Float16* __restrict__ th, _Float16* __restrict__ tl) {
  int i = blockIdx.x * blockDim.x + threadIdx.x;
  if (i >= K * M) return;
  int k = i / M, m = i - k * M;
  float x = W[i];
  _Float16 h = (_Float16)x;
  th[(size_t)m * K + k] = h;
  tl[(size_t)m * K + k] = (_Float16)(x - (float)h);
}

// ---------------------------------------------------------------- fp16x2 split MFMA GEMM
// C[n,M] = concat(A0,A1,A2) @ W (+row_scale)(+bias)(+relu).  All A chunks fp16.
// W split into fp16 hi/lo: a*w ~= a*wh + a*wl (2 MFMAs, fp32 accumulate).
// Block 128x128, BK=32, 4 waves each 64x64 (4x4 tiles of 16x16x32 f16 MFMA).
// Staging: global_load_lds width=16, LINEAR LDS (no pad — required by gload_lds).
// Bank-conflict fix per rule #21: swizzle the per-lane GLOBAL source slot
// (lslot ^ (row&3)) and apply the same XOR on the ds_read address. 8-way -> 4-way.
// row_scale: C[r,:] *= row_scale[r] before bias (folds dinv pre-scale of next agg).
// out_half: write fp16, else fp32.

#define BM 128
#define BN 128
#define BK 32

__global__ __launch_bounds__(256) void gemm_f16_kernel(
    const _Float16* __restrict__ A0, int K0, const _Float16* __restrict__ A1, int K1,
    const _Float16* __restrict__ A2, int K2, const _Float16* __restrict__ Bth,
    const _Float16* __restrict__ Btl, int Ktot, int M, const float* __restrict__ bias,
    const float* __restrict__ row_scale, void* __restrict__ Cmat, int relu, int out_half,
    int nrows) {
  __shared__ _Float16 As[BM * BK];    // [row][32] row-major, 64 B rows
  __shared__ _Float16 Bs_h[BN * BK];
  __shared__ _Float16 Bs_l[BN * BK];

  const int tid = threadIdx.x;
  const int lane = tid & 63;
  const int wv = tid >> 6;
  const int mBase = (wv >> 1) * 64;
  const int nBase = (wv & 1) * 64;
  const int ml = lane & 15;
  const int quad = lane >> 4;
  const int rowBase = blockIdx.x * BM;
  const int colBase = blockIdx.y * BN;

  // staging geometry: wave wv stages tile rows [wv*32, wv*32+32) of A, Bh, Bl.
  // Each gload_lds call covers 16 rows: lane -> row lrow, 16B slot lslot (linear dest).
  const int lrow = lane >> 2;  // 0..15
  const int lslot = lane & 3;  // 16B slot within 64B row

  f32x4 acc[4][4];
  const f32x4 zero = {0.f, 0.f, 0.f, 0.f};
#pragma unroll
  for (int i = 0; i < 4; i++)
#pragma unroll
    for (int j = 0; j < 4; j++) acc[i][j] = zero;

  for (int k0 = 0; k0 < Ktot; k0 += BK) {
    const _Float16* Ap;
    int kl, Kp;
    if (k0 < K0) {
      Ap = A0; kl = k0; Kp = K0;
    } else if (k0 < K0 + K1) {
      Ap = A1; kl = k0 - K0; Kp = K1;
    } else {
      Ap = A2; kl = k0 - K0 - K1; Kp = K2;
    }
#pragma unroll
    for (int c = 0; c < 2; c++) {
      int trow = wv * 32 + c * 16 + lrow;       // tile row 0..127
      int sws = lslot ^ (trow & 3);             // swizzled global 16B slot
      size_t ldsoff = (size_t)(wv * 32 + c * 16) * 64;  // bytes, wave-uniform
      // A (row clamped: garbage rows only pollute skipped output rows)
      int gr = rowBase + trow;
      if (gr > nrows - 1) gr = nrows - 1;
      gload_lds16(Ap + (size_t)gr * Kp + kl + sws * 8, (char*)As + ldsoff);
      // B hi / lo
      const _Float16* bh = Bth + (size_t)(colBase + trow) * Ktot + k0 + sws * 8;
      const _Float16* blp = Btl + (size_t)(colBase + trow) * Ktot + k0 + sws * 8;
      gload_lds16(bh, (char*)Bs_h + ldsoff);
      gload_lds16(blp, (char*)Bs_l + ldsoff);
    }
    __syncthreads();

    f16x8 av[4], bh[4], bl[4];
#pragma unroll
    for (int nt = 0; nt < 4; nt++) {
      int nrow = nBase + nt * 16 + ml;
      int boff = nrow * 32 + ((quad ^ (nrow & 3)) << 3);
      bh[nt] = *(const f16x8*)&Bs_h[boff];
      bl[nt] = *(const f16x8*)&Bs_l[boff];
    }
#pragma unroll
    for (int mt = 0; mt < 4; mt++) {
      int mrow = mBase + mt * 16 + ml;
      int aoff = mrow * 32 + ((quad ^ (mrow & 3)) << 3);
      av[mt] = *(const f16x8*)&As[aoff];
    }
#pragma unroll
    for (int mt = 0; mt < 4; mt++)
#pragma unroll
      for (int nt = 0; nt < 4; nt++) {
        acc[mt][nt] = __builtin_amdgcn_mfma_f32_16x16x32_f16(av[mt], bh[nt], acc[mt][nt], 0, 0, 0);
        acc[mt][nt] = __builtin_amdgcn_mfma_f32_16x16x32_f16(av[mt], bl[nt], acc[mt][nt], 0, 0, 0);
      }
    __syncthreads();
  }

  // epilogue: C/D layout col=lane&15, row=quad*4+reg
#pragma unroll
  for (int nt = 0; nt < 4; nt++) {
    int col = colBase + nBase + nt * 16 + ml;
    float bv = bias ? bias[col] : 0.f;
#pragma unroll
    for (int mt = 0; mt < 4; mt++) {
      int row0 = rowBase + mBase + mt * 16 + quad * 4;
#pragma unroll
      for (int r = 0; r < 4; r++) {
        int grow = row0 + r;
        if (grow >= nrows) continue;
        float v = acc[mt][nt][r];
        if (row_scale) v *= row_scale[grow];
        v += bv;
        if (relu) v = fmaxf(v, 0.f);
        if (out_half) {
          ((_Float16*)Cmat)[(size_t)grow * M + col] = (_Float16)v;
        } else {
          ((float*)Cmat)[(size_t)grow * M + col] = v;
        }
      }
    }
  }
}

// ---------------------------------------------------------------- launch

extern "C" void kernel_launch(void* const* d_in, const int* in_sizes, int n_in, void* d_out,
                              int out_size, void* d_ws, size_t ws_size, hipStream_t stream) {
  const float* x_self     = (const float*)d_in[0];
  const float* x_neighbor = (const float*)d_in[1];
  const void*  edge_index = d_in[2];
  const float* W_in_self  = (const float*)d_in[3];
  const float* b_in_self  = (const float*)d_in[4];
  const float* W_out_self = (const float*)d_in[5];
  const float* b_out_self = (const float*)d_in[6];
  const float* Wg1        = (const float*)d_in[7];
  const float* bg1        = (const float*)d_in[8];
  const float* Wg2        = (const float*)d_in[9];
  const float* bg2        = (const float*)d_in[10];
  const float* W_out      = (const float*)d_in[11];
  const float* b_out      = (const float*)d_in[12];
  float* out = (float*)d_out;

  char* ws = (char*)d_ws;
  size_t off = 0;
  auto alloc = [&](size_t bytes) -> void* {
    void* p = ws + off;
    off = (off + bytes + 255) & ~(size_t)255;
    return p;
  };
  int* counts = (int*)alloc((size_t)2 * NNODES * 4);  // counts + fillc contiguous
  int* fillc  = counts + NNODES;
  int*   offs   = (int*)alloc((size_t)(NNODES + 1) * 4);
  int*   csr    = (int*)alloc((size_t)NEDGES * 4);
  int*   bsums  = (int*)alloc(4096);
  int*   flag   = (int*)alloc(256);
  float* dinv   = (float*)alloc((size_t)NNODES * 4);
  _Float16* wt1h = (_Float16*)alloc(32768 * 2);  // W_in_self  K=128 M=256
  _Float16* wt1l = (_Float16*)alloc(32768 * 2);
  _Float16* wt2h = (_Float16*)alloc(49152 * 2);  // W_out_self K=384 M=128
  _Float16* wt2l = (_Float16*)alloc(49152 * 2);
  _Float16* wt3h = (_Float16*)alloc(32768 * 2);  // Wg1        K=128 M=256
  _Float16* wt3l = (_Float16*)alloc(32768 * 2);
  _Float16* wt4h = (_Float16*)alloc(32768 * 2);  // Wg2        K=256 M=128
  _Float16* wt4l = (_Float16*)alloc(32768 * 2);
  _Float16* wt5h = (_Float16*)alloc(65536 * 2);  // W_out      K=512 M=128
  _Float16* wt5l = (_Float16*)alloc(65536 * 2);
  float* bufA = (float*)alloc((size_t)NNODES * 256 * 4);
  float* bufB = (float*)alloc((size_t)NNODES * 256 * 4);
  (void)ws_size;

  const int nb = (NNODES + SCAN_TILE - 1) / SCAN_TILE;  // 98
  const int gridRows = (NNODES + BM - 1) / BM;          // 782

  detect_kernel<<<1, 64, 0, stream>>>((const unsigned int*)edge_index, flag);
  zero_int_kernel<<<(2 * NNODES + 255) / 256, 256, 0, stream>>>(counts, 2 * NNODES);
  hist_kernel<<<1024, 256, 0, stream>>>(edge_index, flag, counts);
  dinv_kernel<<<(NNODES + 255) / 256, 256, 0, stream>>>(counts, dinv);
  scan_reduce_kernel<<<nb, SCAN_B, 0, stream>>>(counts, bsums);
  scan_bsums_kernel<<<1, 64, 0, stream>>>(bsums, offs, nb);
  scan_write_kernel<<<nb, SCAN_B, 0, stream>>>(counts, bsums, offs);
  fill_kernel<<<1024, 256, 0, stream>>>(edge_index, flag, offs, fillc, csr);

  wprep_f16_kernel<<<(32768 + 255) / 256, 256, 0, stream>>>(W_in_self, 128, 256, wt1h, wt1l);
  wprep_f16_kernel<<<(49152 + 255) / 256, 256, 0, stream>>>(W_out_self, 384, 128, wt2h, wt2l);
  wprep_f16_kernel<<<(32768 + 255) / 256, 256, 0, stream>>>(Wg1, 128, 256, wt3h, wt3l);
  wprep_f16_kernel<<<(32768 + 255) / 256, 256, 0, stream>>>(Wg2, 256, 128, wt4h, wt4l);
  wprep_f16_kernel<<<(65536 + 255) / 256, 256, 0, stream>>>(W_out, 512, 128, wt5h, wt5l);

  // ---- fp16 copies of the fp32 inputs (in bufB's permanently-free top half) ----
  // bufB layout: [0 .. N*128 floats) = ybuf/g1 region; [N*128 .. N*256 floats) free:
  //   xs16 = 25.6 MB, xn16 = 25.6 MB (live: xs16 thru GEMM-2, xn16 thru GEMM-6).
  _Float16* xs16 = (_Float16*)(bufB + (size_t)NNODES * 128);
  _Float16* xn16 = xs16 + (size_t)NNODES * 128;
  xcvt_kernel<<<(NNODES * 32 + 255) / 256, 256, 0, stream>>>(x_self, (f16x4*)xs16, NNODES * 32);
  xcvt_kernel<<<(NNODES * 32 + 255) / 256, 256, 0, stream>>>(x_neighbor, (f16x4*)xn16,
                                                             NNODES * 32);

  // ---- dense self branch ----
  // l1 = relu(xs16 @ W1 + b1) stored fp16 [N,256] in bufA
  _Float16* l1 = (_Float16*)bufA;
  gemm_f16_kernel<<<dim3(gridRows, 2), 256, 0, stream>>>(
      xs16, 128, nullptr, 0, nullptr, 0, wt1h, wt1l, 128, 256, b_in_self, nullptr, l1, 1, 1,
      NNODES);
  gemm_f16_kernel<<<dim3(gridRows, 1), 256, 0, stream>>>(
      xs16, 128, l1, 256, nullptr, 0, wt2h, wt2l, 384, 128, b_out_self, nullptr, out, 0, 0,
      NNODES);

  // ---- GCN branch (A_norm @ (X W) == (A_norm @ X) W), all intermediates fp16 ----
  // Buffer timeline:
  //   ybuf = bufB[0:25.6MB] f16 (dead after agg1)
  //   aggx = bufA[0:25.6MB] f16 (bufA free after GEMM-2; dead after GEMM-3)
  //   g1   = bufB[0:51.2MB] f16 (overwrites ybuf; live through GEMM-6)
  //   xw2  = bufA[0:25.6MB] f16 (dead after agg2)
  //   g2   = bufA+51.2MB [N,128] f16 (no overlap with xw2)
  _Float16* ybuf = (_Float16*)bufB;
  _Float16* aggx = (_Float16*)bufA;
  _Float16* g1   = (_Float16*)bufB;
  _Float16* xw2  = (_Float16*)bufA;
  _Float16* g2   = (_Float16*)bufA + (size_t)NNODES * 128;

  prescale16_kernel<<<(NNODES * 32 + 255) / 256, 256, 0, stream>>>((const f16x4*)xn16, dinv,
                                                                   (f16x4*)ybuf);
  aggregate_half_kernel<<<NNODES / 4, 256, 0, stream>>>((const f16x2*)ybuf, aggx, 1, offs, csr,
                                                        dinv, nullptr);
  gemm_f16_kernel<<<dim3(gridRows, 2), 256, 0, stream>>>(
      aggx, 128, nullptr, 0, nullptr, 0, wt3h, wt3l, 128, 256, bg1, nullptr, g1, 0, 1, NNODES);
  // xw2 = (fp16)((g1 @ Wg2) * dinv[row])  (pre-scale for agg2 folded into epilogue)
  gemm_f16_kernel<<<dim3(gridRows, 1), 256, 0, stream>>>(
      g1, 256, nullptr, 0, nullptr, 0, wt4h, wt4l, 256, 128, nullptr, dinv, xw2, 0, 1, NNODES);
  aggregate_half_kernel<<<NNODES / 4, 256, 0, stream>>>((const f16x2*)xw2, g2, 1, offs, csr,
                                                        dinv, bg2);
  gemm_f16_kernel<<<dim3(gridRows, 1), 256, 0, stream>>>(
      xn16, 128, g1, 256, g2, 128, wt5h, wt5l, 512, 128, b_out, nullptr,
      out + (size_t)NNODES * 128, 0, 0, NNODES);
}

// Round 7
// 760.944 us; speedup vs baseline: 1.0925x; 1.0367x over previous
//
#include <hip/hip_runtime.h>
#include <cstdint>
#include <cstddef>

#define NNODES 100000
#define NEDGES 1600000
// D = 128, C = 128 (hard-coded below)

typedef float f32x4 __attribute__((ext_vector_type(4)));
typedef unsigned int u32;
// native fp16 (no hip_fp16.h dependency — clang _Float16)
typedef _Float16 f16x2 __attribute__((ext_vector_type(2)));
typedef _Float16 f16x4 __attribute__((ext_vector_type(4)));
typedef _Float16 f16x8 __attribute__((ext_vector_type(8)));

// async global->LDS, 16B per lane: dest = lds_base + lane*16 (linear), src per-lane.
__device__ __forceinline__ void gload_lds16(const void* g, void* l) {
  __builtin_amdgcn_global_load_lds((const __attribute__((address_space(1))) u32*)g,
                                   (__attribute__((address_space(3))) u32*)l, 16, 0, 0);
}

// ---------------------------------------------------------------- utilities

__global__ void zero_int_kernel(int* __restrict__ p, int n) {
  int i = blockIdx.x * blockDim.x + threadIdx.x;
  if (i < n) p[i] = 0;
}

// int64 vs int32 edge_index detection (high words all zero => int64)
__global__ void detect_kernel(const unsigned int* __restrict__ ei, int* __restrict__ flag) {
  unsigned int v = ei[2 * threadIdx.x + 1];
  unsigned long long b = __ballot(v != 0u);
  if (threadIdx.x == 0) *flag = (b == 0ull) ? 1 : 0;
}

__device__ __forceinline__ int edge_val(const void* ei, int is64, long long idx) {
  if (is64) return (int)((const long long*)ei)[idx];
  return ((const int*)ei)[idx];
}

// ---------------------------------------------------------------- degree / CSR

__global__ void hist_kernel(const void* __restrict__ ei, const int* __restrict__ flag,
                            int* __restrict__ counts) {
  const int is64 = *flag;
  for (long long e = (long long)blockIdx.x * blockDim.x + threadIdx.x; e < NEDGES;
       e += (long long)gridDim.x * blockDim.x) {
    int d = edge_val(ei, is64, NEDGES + e);
    atomicAdd(&counts[d], 1);
  }
}

__global__ void dinv_kernel(const int* __restrict__ counts, float* __restrict__ dinv) {
  int i = blockIdx.x * blockDim.x + threadIdx.x;
  if (i < NNODES) dinv[i] = rsqrtf((float)(counts[i] + 1));  // +1 self loop
}

#define SCAN_B 256
#define SCAN_TILE 1024

__global__ void scan_reduce_kernel(const int* __restrict__ counts, int* __restrict__ bsums) {
  __shared__ int sd[SCAN_B];
  int t = threadIdx.x;
  int base = blockIdx.x * SCAN_TILE + t * 4;
  int s = 0;
#pragma unroll
  for (int i = 0; i < 4; i++) {
    int idx = base + i;
    if (idx < NNODES) s += counts[idx];
  }
  sd[t] = s;
  __syncthreads();
  for (int o = SCAN_B / 2; o > 0; o >>= 1) {
    if (t < o) sd[t] += sd[t + o];
    __syncthreads();
  }
  if (t == 0) bsums[blockIdx.x] = sd[0];
}

__global__ void scan_bsums_kernel(int* __restrict__ bsums, int* __restrict__ offs, int nb) {
  if (threadIdx.x == 0 && blockIdx.x == 0) {
    int run = 0;
    for (int b = 0; b < nb; b++) {
      int v = bsums[b];
      bsums[b] = run;
      run += v;
    }
    offs[NNODES] = run;
  }
}

__global__ void scan_write_kernel(const int* __restrict__ counts, const int* __restrict__ bsums,
                                  int* __restrict__ offs) {
  __shared__ int sd[SCAN_B];
  int t = threadIdx.x;
  int base = blockIdx.x * SCAN_TILE + t * 4;
  int v[4];
  int s = 0;
#pragma unroll
  for (int i = 0; i < 4; i++) {
    int idx = base + i;
    v[i] = (idx < NNODES) ? counts[idx] : 0;
    s += v[i];
  }
  sd[t] = s;
  __syncthreads();
  for (int o = 1; o < SCAN_B; o <<= 1) {
    int x = (t >= o) ? sd[t - o] : 0;
    __syncthreads();
    sd[t] += x;
    __syncthreads();
  }
  int run = sd[t] - s + bsums[blockIdx.x];
#pragma unroll
  for (int i = 0; i < 4; i++) {
    int idx = base + i;
    if (idx < NNODES) {
      offs[idx] = run;
      run += v[i];
    }
  }
}

// ---------------------------------------------------------------- bucketed CSR fill
// Replaces the random-scatter fill (107 MB sector-amplified writes -> ~20 MB efficient).
// Pass A (bucket_kernel): partition edges into 391 dst-buckets of 256 nodes each.
//   Per block: LDS hist -> one global reservation per bucket -> LDS-rank placement.
//   Writes 8B (src,dst) pairs in per-(block,bucket) contiguous runs (~128B).
// Pass B (fillwin_kernel): block b owns csr window [offs[b*256], offs[(b+1)*256)).
//   Scatters its bucket's pairs inside an LDS window, writes back fully coalesced.
// Overflow fallbacks (never hit for Poisson(16) input) keep correctness unconditional.

#define BK_SHIFT 8
#define NBUCK 391   // ceil(NNODES / 256)
#define BCAP 8192   // pairs per bucket (mean 4096, +64 sigma)
#define WCAP 12288  // csr window ints in LDS (mean 4096, +128 sigma)

__global__ __launch_bounds__(256) void bucket_kernel(
    const void* __restrict__ ei, const int* __restrict__ flag, const int* __restrict__ offs,
    int* __restrict__ fillc, int* __restrict__ gcount,
    unsigned long long* __restrict__ bpairs, int* __restrict__ csr) {
  __shared__ int lcount[NBUCK];
  __shared__ int gbase[NBUCK];
  __shared__ int lcur[NBUCK];
  const int is64 = *flag;
  const int chunk = NEDGES / 256;  // 6250 (grid must be 256 blocks)
  const long long e0 = (long long)blockIdx.x * chunk;
  const long long e1 = e0 + chunk;
  for (int i = threadIdx.x; i < NBUCK; i += 256) {
    lcount[i] = 0;
    lcur[i] = 0;
  }
  __syncthreads();
  for (long long e = e0 + threadIdx.x; e < e1; e += 256) {
    int d = edge_val(ei, is64, NEDGES + e);
    atomicAdd(&lcount[d >> BK_SHIFT], 1);
  }
  __syncthreads();
  for (int i = threadIdx.x; i < NBUCK; i += 256) {
    int c = lcount[i];
    gbase[i] = c ? atomicAdd(&gcount[i], c) : 0;
  }
  __syncthreads();
  for (long long e = e0 + threadIdx.x; e < e1; e += 256) {
    int s = edge_val(ei, is64, e);
    int d = edge_val(ei, is64, NEDGES + e);
    int b = d >> BK_SHIFT;
    int pos = gbase[b] + atomicAdd(&lcur[b], 1);
    if (pos < BCAP) {
      bpairs[(size_t)b * BCAP + pos] =
          ((unsigned long long)(unsigned)d << 32) | (unsigned)s;
    } else {
      // bucket overflow: direct scatter (slow path, correctness only)
      int p = offs[d] + atomicAdd(&fillc[d], 1);
      csr[p] = s;
    }
  }
}

__global__ __launch_bounds__(256) void fillwin_kernel(
    const unsigned long long* __restrict__ bpairs, const int* __restrict__ gcount,
    const int* __restrict__ offs, int* __restrict__ fillc, int* __restrict__ csr) {
  __shared__ int win[WCAP];
  __shared__ int nfill[256];
  const int b = blockIdx.x;
  const int nlo = b << BK_SHIFT;
  const int nhi = min(nlo + 256, NNODES);
  const int base = offs[nlo];
  const int W = offs[nhi] - base;
  int cnt = gcount[b];
  if (cnt > BCAP) cnt = BCAP;
  if (W <= WCAP) {
    if ((int)threadIdx.x < nhi - nlo) nfill[threadIdx.x] = fillc[nlo + threadIdx.x];
    // preserve any fallback-written cells (and fill garbage elsewhere — every window
    // cell is either fallback-filled or pair-filled below, totals match offs)
    for (int i = threadIdx.x; i < W; i += 256) win[i] = csr[base + i];
    __syncthreads();
    for (int i = threadIdx.x; i < cnt; i += 256) {
      unsigned long long v = bpairs[(size_t)b * BCAP + i];
      int d = (int)(v >> 32);
      int s = (int)(v & 0xffffffffull);
      int p = offs[d] - base + atomicAdd(&nfill[d - nlo], 1);
      win[p] = s;
    }
    __syncthreads();
    for (int i = threadIdx.x; i < W; i += 256) csr[base + i] = win[i];
  } else {
    // window overflow: direct scatter (continues fillc from pass-A fallback)
    for (int i = threadIdx.x; i < cnt; i += 256) {
      unsigned long long v = bpairs[(size_t)b * BCAP + i];
      int d = (int)(v >> 32);
      int s = (int)(v & 0xffffffffull);
      int p = offs[d] + atomicAdd(&fillc[d], 1);
      csr[p] = s;
    }
  }
}

// ---------------------------------------------------------------- fp32 -> fp16 convert
// y[i] = (fp16) x[i], vectorized float4 -> f16x4

__global__ void xcvt_kernel(const float* __restrict__ x, f16x4* __restrict__ y, int n4) {
  int i = blockIdx.x * blockDim.x + threadIdx.x;
  if (i >= n4) return;
  float4 v = ((const float4*)x)[i];
  f16x4 h;
  h[0] = (_Float16)v.x;
  h[1] = (_Float16)v.y;
  h[2] = (_Float16)v.z;
  h[3] = (_Float16)v.w;
  y[i] = h;
}

// ---------------------------------------------------------------- prescale (fp16 in/out)
// y[i,:] = (fp16) dinv[i] * x16[i,:]

__global__ void prescale16_kernel(const f16x4* __restrict__ x, const float* __restrict__ dinv,
                                  f16x4* __restrict__ y) {
  int i = blockIdx.x * blockDim.x + threadIdx.x;  // over NNODES*32 f16x4
  if (i >= NNODES * 32) return;
  int row = i >> 5;
  float s = dinv[row];
  f16x4 v = x[i];
  f16x4 h;
  h[0] = (_Float16)((float)v[0] * s);
  h[1] = (_Float16)((float)v[1] * s);
  h[2] = (_Float16)((float)v[2] * s);
  h[3] = (_Float16)((float)v[3] * s);
  y[i] = h;
}

// ---------------------------------------------------------------- aggregation (gather, fp16 in)
// Input rows are PRE-SCALED fp16: y_j = (fp16)(dinv[j]*x_j).   256 B/row.
// out[i,:] = dinv[i] * (y_i + sum_{j in nbr(i)} y_j) + bias   (fp32 accumulate)
// out_half: write fp16 (feeds the next GEMM's fp16 A path), else fp32.
// One wave per node, f16x2 per lane, 8-way unrolled gathers (4 fp32 accumulators).

__device__ __forceinline__ float2 f16x2_to_f32(f16x2 h) {
  return make_float2((float)h[0], (float)h[1]);
}

__global__ __launch_bounds__(256) void aggregate_half_kernel(
    const f16x2* __restrict__ in, void* __restrict__ out, int out_half,
    const int* __restrict__ offs, const int* __restrict__ csr, const float* __restrict__ dinv,
    const float* __restrict__ bias) {
  int node = blockIdx.x * 4 + (threadIdx.x >> 6);
  if (node >= NNODES) return;
  int ch = threadIdx.x & 63;  // f16x2 index within row (64 x f16x2 = 128 cols)
  int beg = offs[node], end = offs[node + 1];

  // self term (pre-scaled row)
  float2 a0 = f16x2_to_f32(in[(size_t)node * 64 + ch]);
  float2 a1 = make_float2(0.f, 0.f);
  float2 a2 = make_float2(0.f, 0.f);
  float2 a3 = make_float2(0.f, 0.f);

  int p = beg;
  for (; p + 8 <= end; p += 8) {
    int j0 = csr[p + 0], j1 = csr[p + 1], j2 = csr[p + 2], j3 = csr[p + 3];
    int j4 = csr[p + 4], j5 = csr[p + 5], j6 = csr[p + 6], j7 = csr[p + 7];
    f16x2 h0 = in[(size_t)j0 * 64 + ch];
    f16x2 h1 = in[(size_t)j1 * 64 + ch];
    f16x2 h2 = in[(size_t)j2 * 64 + ch];
    f16x2 h3 = in[(size_t)j3 * 64 + ch];
    f16x2 h4 = in[(size_t)j4 * 64 + ch];
    f16x2 h5 = in[(size_t)j5 * 64 + ch];
    f16x2 h6 = in[(size_t)j6 * 64 + ch];
    f16x2 h7 = in[(size_t)j7 * 64 + ch];
    float2 v0 = f16x2_to_f32(h0);
    float2 v1 = f16x2_to_f32(h1);
    float2 v2 = f16x2_to_f32(h2);
    float2 v3 = f16x2_to_f32(h3);
    float2 v4 = f16x2_to_f32(h4);
    float2 v5 = f16x2_to_f32(h5);
    float2 v6 = f16x2_to_f32(h6);
    float2 v7 = f16x2_to_f32(h7);
    a0.x += v0.x; a0.y += v0.y;
    a1.x += v1.x; a1.y += v1.y;
    a2.x += v2.x; a2.y += v2.y;
    a3.x += v3.x; a3.y += v3.y;
    a0.x += v4.x; a0.y += v4.y;
    a1.x += v5.x; a1.y += v5.y;
    a2.x += v6.x; a2.y += v6.y;
    a3.x += v7.x; a3.y += v7.y;
  }
  for (; p + 2 <= end; p += 2) {
    int j0 = csr[p], j1 = csr[p + 1];
    float2 v0 = f16x2_to_f32(in[(size_t)j0 * 64 + ch]);
    float2 v1 = f16x2_to_f32(in[(size_t)j1 * 64 + ch]);
    a0.x += v0.x; a0.y += v0.y;
    a1.x += v1.x; a1.y += v1.y;
  }
  if (p < end) {
    float2 v0 = f16x2_to_f32(in[(size_t)csr[p] * 64 + ch]);
    a0.x += v0.x; a0.y += v0.y;
  }

  float di = dinv[node];
  int c = ch * 2;
  float2 r;
  r.x = di * (a0.x + a1.x + a2.x + a3.x);
  r.y = di * (a0.y + a1.y + a2.y + a3.y);
  if (bias) {
    r.x += bias[c];
    r.y += bias[c + 1];
  }
  if (out_half) {
    f16x2 h;
    h[0] = (_Float16)r.x;
    h[1] = (_Float16)r.y;
    ((f16x2*)out)[(size_t)node * 64 + ch] = h;
  } else {
    *(float2*)((float*)out + (size_t)node * 128 + c) = r;
  }
}

// ---------------------------------------------------------------- weight prep
// W [K][M] fp32  ->  Wt_h/Wt_l [M][K] fp16 (transposed, split: w = wh + wl, wl ~ 2^-11 w)

__global__ void wprep_f16_kernel(const float* __restrict__ W, int K, int M,
                                 _Float16* __restrict__ th, _Float16* __restrict__ tl) {
  int i = blockIdx.x * blockDim.x + threadIdx.x;
  if (i >= K * M) return;
  int k = i / M, m = i - k * M;
  float x = W[i];
  _Float16 h = (_Float16)x;
  th[(size_t)m * K + k] = h;
  tl[(size_t)m * K + k] = (_Float16)(x - (float)h);
}

// ---------------------------------------------------------------- fp16x2 split MFMA GEMM
// C[n,M] = concat(A0,A1,A2) @ W (+row_scale)(+bias)(+relu).  All A chunks fp16.
// W split into fp16 hi/lo: a*w ~= a*wh + a*wl (2 MFMAs, fp32 accumulate).
// Block 128x128, BK=32, 4 waves each 64x64 (4x4 tiles of 16x16x32 f16 MFMA).
// Staging: global_load_lds width=16, LINEAR LDS (no pad — required by gload_lds).
// Bank-conflict fix per rule #21: swizzle the per-lane GLOBAL source slot
// (lslot ^ (row&3)) and apply the same XOR on the ds_read address. 8-way -> 4-way.
// row_scale: C[r,:] *= row_scale[r] before bias (folds dinv pre-scale of next agg).
// out_half: write fp16, else fp32.

#define BM 128
#define BN 128
#define BK 32

__global__ __launch_bounds__(256) void gemm_f16_kernel(
    const _Float16* __restrict__ A0, int K0, const _Float16* __restrict__ A1, int K1,
    const _Float16* __restrict__ A2, int K2, const _Float16* __restrict__ Bth,
    const _Float16* __restrict__ Btl, int Ktot, int M, const float* __restrict__ bias,
    const float* __restrict__ row_scale, void* __restrict__ Cmat, int relu, int out_half,
    int nrows) {
  __shared__ _Float16 As[BM * BK];    // [row][32] row-major, 64 B rows
  __shared__ _Float16 Bs_h[BN * BK];
  __shared__ _Float16 Bs_l[BN * BK];

  const int tid = threadIdx.x;
  const int lane = tid & 63;
  const int wv = tid >> 6;
  const int mBase = (wv >> 1) * 64;
  const int nBase = (wv & 1) * 64;
  const int ml = lane & 15;
  const int quad = lane >> 4;
  const int rowBase = blockIdx.x * BM;
  const int colBase = blockIdx.y * BN;

  // staging geometry: wave wv stages tile rows [wv*32, wv*32+32) of A, Bh, Bl.
  const int lrow = lane >> 2;  // 0..15
  const int lslot = lane & 3;  // 16B slot within 64B row

  f32x4 acc[4][4];
  const f32x4 zero = {0.f, 0.f, 0.f, 0.f};
#pragma unroll
  for (int i = 0; i < 4; i++)
#pragma unroll
    for (int j = 0; j < 4; j++) acc[i][j] = zero;

  for (int k0 = 0; k0 < Ktot; k0 += BK) {
    const _Float16* Ap;
    int kl, Kp;
    if (k0 < K0) {
      Ap = A0; kl = k0; Kp = K0;
    } else if (k0 < K0 + K1) {
      Ap = A1; kl = k0 - K0; Kp = K1;
    } else {
      Ap = A2; kl = k0 - K0 - K1; Kp = K2;
    }
#pragma unroll
    for (int c = 0; c < 2; c++) {
      int trow = wv * 32 + c * 16 + lrow;       // tile row 0..127
      int sws = lslot ^ (trow & 3);             // swizzled global 16B slot
      size_t ldsoff = (size_t)(wv * 32 + c * 16) * 64;  // bytes, wave-uniform
      // A (row clamped: garbage rows only pollute skipped output rows)
      int gr = rowBase + trow;
      if (gr > nrows - 1) gr = nrows - 1;
      gload_lds16(Ap + (size_t)gr * Kp + kl + sws * 8, (char*)As + ldsoff);
      // B hi / lo
      const _Float16* bh = Bth + (size_t)(colBase + trow) * Ktot + k0 + sws * 8;
      const _Float16* blp = Btl + (size_t)(colBase + trow) * Ktot + k0 + sws * 8;
      gload_lds16(bh, (char*)Bs_h + ldsoff);
      gload_lds16(blp, (char*)Bs_l + ldsoff);
    }
    __syncthreads();

    f16x8 av[4], bh[4], bl[4];
#pragma unroll
    for (int nt = 0; nt < 4; nt++) {
      int nrow = nBase + nt * 16 + ml;
      int boff = nrow * 32 + ((quad ^ (nrow & 3)) << 3);
      bh[nt] = *(const f16x8*)&Bs_h[boff];
      bl[nt] = *(const f16x8*)&Bs_l[boff];
    }
#pragma unroll
    for (int mt = 0; mt < 4; mt++) {
      int mrow = mBase + mt * 16 + ml;
      int aoff = mrow * 32 + ((quad ^ (mrow & 3)) << 3);
      av[mt] = *(const f16x8*)&As[aoff];
    }
#pragma unroll
    for (int mt = 0; mt < 4; mt++)
#pragma unroll
      for (int nt = 0; nt < 4; nt++) {
        acc[mt][nt] = __builtin_amdgcn_mfma_f32_16x16x32_f16(av[mt], bh[nt], acc[mt][nt], 0, 0, 0);
        acc[mt][nt] = __builtin_amdgcn_mfma_f32_16x16x32_f16(av[mt], bl[nt], acc[mt][nt], 0, 0, 0);
      }
    __syncthreads();
  }

  // epilogue: C/D layout col=lane&15, row=quad*4+reg
#pragma unroll
  for (int nt = 0; nt < 4; nt++) {
    int col = colBase + nBase + nt * 16 + ml;
    float bv = bias ? bias[col] : 0.f;
#pragma unroll
    for (int mt = 0; mt < 4; mt++) {
      int row0 = rowBase + mBase + mt * 16 + quad * 4;
#pragma unroll
      for (int r = 0; r < 4; r++) {
        int grow = row0 + r;
        if (grow >= nrows) continue;
        float v = acc[mt][nt][r];
        if (row_scale) v *= row_scale[grow];
        v += bv;
        if (relu) v = fmaxf(v, 0.f);
        if (out_half) {
          ((_Float16*)Cmat)[(size_t)grow * M + col] = (_Float16)v;
        } else {
          ((float*)Cmat)[(size_t)grow * M + col] = v;
        }
      }
    }
  }
}

// ---------------------------------------------------------------- launch

extern "C" void kernel_launch(void* const* d_in, const int* in_sizes, int n_in, void* d_out,
                              int out_size, void* d_ws, size_t ws_size, hipStream_t stream) {
  const float* x_self     = (const float*)d_in[0];
  const float* x_neighbor = (const float*)d_in[1];
  const void*  edge_index = d_in[2];
  const float* W_in_self  = (const float*)d_in[3];
  const float* b_in_self  = (const float*)d_in[4];
  const float* W_out_self = (const float*)d_in[5];
  const float* b_out_self = (const float*)d_in[6];
  const float* Wg1        = (const float*)d_in[7];
  const float* bg1        = (const float*)d_in[8];
  const float* Wg2        = (const float*)d_in[9];
  const float* bg2        = (const float*)d_in[10];
  const float* W_out      = (const float*)d_in[11];
  const float* b_out      = (const float*)d_in[12];
  float* out = (float*)d_out;

  char* ws = (char*)d_ws;
  size_t off = 0;
  auto alloc = [&](size_t bytes) -> void* {
    void* p = ws + off;
    off = (off + bytes + 255) & ~(size_t)255;
    return p;
  };
  int* counts = (int*)alloc((size_t)2 * NNODES * 4 + 2048);  // counts + fillc + gcount
  int* fillc  = counts + NNODES;
  int* gcount = counts + 2 * NNODES;                         // NBUCK ints
  int*   offs   = (int*)alloc((size_t)(NNODES + 1) * 4);
  int*   csr    = (int*)alloc((size_t)NEDGES * 4);
  int*   bsums  = (int*)alloc(4096);
  int*   flag   = (int*)alloc(256);
  float* dinv   = (float*)alloc((size_t)NNODES * 4);
  _Float16* wt1h = (_Float16*)alloc(32768 * 2);  // W_in_self  K=128 M=256
  _Float16* wt1l = (_Float16*)alloc(32768 * 2);
  _Float16* wt2h = (_Float16*)alloc(49152 * 2);  // W_out_self K=384 M=128
  _Float16* wt2l = (_Float16*)alloc(49152 * 2);
  _Float16* wt3h = (_Float16*)alloc(32768 * 2);  // Wg1        K=128 M=256
  _Float16* wt3l = (_Float16*)alloc(32768 * 2);
  _Float16* wt4h = (_Float16*)alloc(32768 * 2);  // Wg2        K=256 M=128
  _Float16* wt4l = (_Float16*)alloc(32768 * 2);
  _Float16* wt5h = (_Float16*)alloc(65536 * 2);  // W_out      K=512 M=128
  _Float16* wt5l = (_Float16*)alloc(65536 * 2);
  float* bufA = (float*)alloc((size_t)NNODES * 256 * 4);
  float* bufB = (float*)alloc((size_t)NNODES * 256 * 4);
  (void)ws_size;

  // bpairs (25.6 MB) aliases bufA: dead before GEMM-1 writes l1 there.
  unsigned long long* bpairs = (unsigned long long*)bufA;

  const int nb = (NNODES + SCAN_TILE - 1) / SCAN_TILE;  // 98
  const int gridRows = (NNODES + BM - 1) / BM;          // 782

  detect_kernel<<<1, 64, 0, stream>>>((const unsigned int*)edge_index, flag);
  zero_int_kernel<<<(2 * NNODES + 512 + 255) / 256, 256, 0, stream>>>(counts,
                                                                      2 * NNODES + 512);
  hist_kernel<<<1024, 256, 0, stream>>>(edge_index, flag, counts);
  dinv_kernel<<<(NNODES + 255) / 256, 256, 0, stream>>>(counts, dinv);
  scan_reduce_kernel<<<nb, SCAN_B, 0, stream>>>(counts, bsums);
  scan_bsums_kernel<<<1, 64, 0, stream>>>(bsums, offs, nb);
  scan_write_kernel<<<nb, SCAN_B, 0, stream>>>(counts, bsums, offs);
  bucket_kernel<<<256, 256, 0, stream>>>(edge_index, flag, offs, fillc, gcount, bpairs, csr);
  fillwin_kernel<<<NBUCK, 256, 0, stream>>>(bpairs, gcount, offs, fillc, csr);

  wprep_f16_kernel<<<(32768 + 255) / 256, 256, 0, stream>>>(W_in_self, 128, 256, wt1h, wt1l);
  wprep_f16_kernel<<<(49152 + 255) / 256, 256, 0, stream>>>(W_out_self, 384, 128, wt2h, wt2l);
  wprep_f16_kernel<<<(32768 + 255) / 256, 256, 0, stream>>>(Wg1, 128, 256, wt3h, wt3l);
  wprep_f16_kernel<<<(32768 + 255) / 256, 256, 0, stream>>>(Wg2, 256, 128, wt4h, wt4l);
  wprep_f16_kernel<<<(65536 + 255) / 256, 256, 0, stream>>>(W_out, 512, 128, wt5h, wt5l);

  // ---- fp16 copies of the fp32 inputs (in bufB's permanently-free top half) ----
  _Float16* xs16 = (_Float16*)(bufB + (size_t)NNODES * 128);
  _Float16* xn16 = xs16 + (size_t)NNODES * 128;
  xcvt_kernel<<<(NNODES * 32 + 255) / 256, 256, 0, stream>>>(x_self, (f16x4*)xs16, NNODES * 32);
  xcvt_kernel<<<(NNODES * 32 + 255) / 256, 256, 0, stream>>>(x_neighbor, (f16x4*)xn16,
                                                             NNODES * 32);

  // ---- dense self branch ----
  // l1 = relu(xs16 @ W1 + b1) stored fp16 [N,256] in bufA (bpairs dead by now)
  _Float16* l1 = (_Float16*)bufA;
  gemm_f16_kernel<<<dim3(gridRows, 2), 256, 0, stream>>>(
      xs16, 128, nullptr, 0, nullptr, 0, wt1h, wt1l, 128, 256, b_in_self, nullptr, l1, 1, 1,
      NNODES);
  gemm_f16_kernel<<<dim3(gridRows, 1), 256, 0, stream>>>(
      xs16, 128, l1, 256, nullptr, 0, wt2h, wt2l, 384, 128, b_out_self, nullptr, out, 0, 0,
      NNODES);

  // ---- GCN branch (A_norm @ (X W) == (A_norm @ X) W), all intermediates fp16 ----
  _Float16* ybuf = (_Float16*)bufB;
  _Float16* aggx = (_Float16*)bufA;
  _Float16* g1   = (_Float16*)bufB;
  _Float16* xw2  = (_Float16*)bufA;
  _Float16* g2   = (_Float16*)bufA + (size_t)NNODES * 128;

  prescale16_kernel<<<(NNODES * 32 + 255) / 256, 256, 0, stream>>>((const f16x4*)xn16, dinv,
                                                                   (f16x4*)ybuf);
  aggregate_half_kernel<<<NNODES / 4, 256, 0, stream>>>((const f16x2*)ybuf, aggx, 1, offs, csr,
                                                        dinv, nullptr);
  gemm_f16_kernel<<<dim3(gridRows, 2), 256, 0, stream>>>(
      aggx, 128, nullptr, 0, nullptr, 0, wt3h, wt3l, 128, 256, bg1, nullptr, g1, 0, 1, NNODES);
  // xw2 = (fp16)((g1 @ Wg2) * dinv[row])  (pre-scale for agg2 folded into epilogue)
  gemm_f16_kernel<<<dim3(gridRows, 1), 256, 0, stream>>>(
      g1, 256, nullptr, 0, nullptr, 0, wt4h, wt4l, 256, 128, nullptr, dinv, xw2, 0, 1, NNODES);
  aggregate_half_kernel<<<NNODES / 4, 256, 0, stream>>>((const f16x2*)xw2, g2, 1, offs, csr,
                                                        dinv, bg2);
  gemm_f16_kernel<<<dim3(gridRows, 1), 256, 0, stream>>>(
      xn16, 128, g1, 256, g2, 128, wt5h, wt5l, 512, 128, b_out, nullptr,
      out + (size_t)NNODES * 128, 0, 0, NNODES);
}